// Round 1
// baseline (377.635 us; speedup 1.0000x reference)
//
#include <hip/hip_runtime.h>
#include <hip/hip_bf16.h>
#include <cstdint>

#define D_DIM 768
#define BM 128
#define BN 128
#define BK 32

typedef short short8 __attribute__((ext_vector_type(8)));
typedef float floatx4 __attribute__((ext_vector_type(4)));

// ---- helpers ----------------------------------------------------------------

__device__ inline unsigned short f2bf(float f) {
  union { float f; unsigned int u; } v; v.f = f;
  unsigned int u = v.u;
  unsigned int rounding = 0x7FFFu + ((u >> 16) & 1u);  // round-to-nearest-even
  u += rounding;
  return (unsigned short)(u >> 16);
}

__device__ inline void lds_load16(const void* g, void* lds) {
#if __has_builtin(__builtin_amdgcn_global_load_lds)
  __builtin_amdgcn_global_load_lds(
      (const __attribute__((address_space(1))) unsigned int*)g,
      (__attribute__((address_space(3))) unsigned int*)lds,
      16, 0, 0);
#else
  // fallback: same layout through VGPRs (lane deposits at base + lane*16)
  int4 v = *(const int4*)g;
  *(int4*)((char*)lds + (size_t)(threadIdx.x & 63) * 16) = v;
#endif
}

// ---- kernel 1: row L2 norm + normalize + cast to bf16 -----------------------
// one wave per row; 768 floats = 192 float4 = 64 lanes x 3 float4

__global__ __launch_bounds__(256) void norm_cast_kernel(
    const float* __restrict__ X, unsigned short* __restrict__ Y, int nrows) {
  int row = blockIdx.x * 4 + (threadIdx.x >> 6);
  int lane = threadIdx.x & 63;
  if (row >= nrows) return;
  const float4* xr = (const float4*)(X + (size_t)row * D_DIM);
  float4 a = xr[lane];
  float4 b = xr[lane + 64];
  float4 c = xr[lane + 128];
  float ss = a.x*a.x + a.y*a.y + a.z*a.z + a.w*a.w
           + b.x*b.x + b.y*b.y + b.z*b.z + b.w*b.w
           + c.x*c.x + c.y*c.y + c.z*c.z + c.w*c.w;
  #pragma unroll
  for (int off = 32; off > 0; off >>= 1) ss += __shfl_xor(ss, off, 64);
  float s = 1.0f / fmaxf(sqrtf(ss), 1e-8f);
  ushort4 o;
  ushort4* yr = (ushort4*)(Y + (size_t)row * D_DIM);
  o.x = f2bf(a.x * s); o.y = f2bf(a.y * s); o.z = f2bf(a.z * s); o.w = f2bf(a.w * s);
  yr[lane] = o;
  o.x = f2bf(b.x * s); o.y = f2bf(b.y * s); o.z = f2bf(b.z * s); o.w = f2bf(b.w * s);
  yr[lane + 64] = o;
  o.x = f2bf(c.x * s); o.y = f2bf(c.y * s); o.z = f2bf(c.z * s); o.w = f2bf(c.w * s);
  yr[lane + 128] = o;
}

// ---- kernel 2: bf16 MFMA GEMM (S = A . B^T) fused with per-row max ----------
// 128x128 block tile, BK=32, 256 threads = 4 waves in 2x2, each wave 64x64
// (4x4 grid of 16x16x32 MFMA). Staging via global_load_lds width=16:
// unpadded row-major LDS tiles [128][32] bf16 (64 B/row, 4 lanes/row).

__global__ __launch_bounds__(256) void gemm_max_kernel(
    const unsigned short* __restrict__ A,   // exn [Nx x 768] bf16 bits
    const unsigned short* __restrict__ B,   // eyn [Ny x 768] bf16 bits
    float* __restrict__ partial,            // [ncb][Nx]
    int Nx) {
  __shared__ unsigned short As[BM * BK];
  __shared__ unsigned short Bs[BN * BK];
  __shared__ float red[2][BM];

  const int tid  = threadIdx.x;
  const int wave = tid >> 6;
  const int lane = tid & 63;
  const int wm = wave >> 1;        // 0..1 row half
  const int wn = wave & 1;         // 0..1 col half
  const int quad = lane >> 4;      // 0..3
  const int l15 = lane & 15;

  const int bm0 = blockIdx.x * BM;
  const int bn0 = blockIdx.y * BN;

  floatx4 acc[4][4];
  #pragma unroll
  for (int mt = 0; mt < 4; ++mt)
    #pragma unroll
    for (int nt = 0; nt < 4; ++nt)
      acc[mt][nt] = (floatx4){0.f, 0.f, 0.f, 0.f};

  // staging: wave handles rows [wave*32, wave*32+32); per instr lane covers
  // row r0 + lane/4, byte (lane&3)*16 in the 64 B row.
  const int srow = lane >> 2;
  const int scol = (lane & 3) * 16;
  const char* gA = (const char*)A + ((size_t)(bm0 + wave * 32 + srow) * D_DIM) * 2 + scol;
  const char* gB = (const char*)B + ((size_t)(bn0 + wave * 32 + srow) * D_DIM) * 2 + scol;
  char* lA0 = (char*)As + (size_t)(wave * 32) * 64;
  char* lA1 = lA0 + 16 * 64;
  char* lB0 = (char*)Bs + (size_t)(wave * 32) * 64;
  char* lB1 = lB0 + 16 * 64;
  const size_t rowskip16 = (size_t)16 * D_DIM * 2;  // 16 rows of global stride

  for (int k0 = 0; k0 < D_DIM; k0 += BK) {
    __syncthreads();  // previous tile fully consumed
    size_t koff = (size_t)k0 * 2;
    lds_load16(gA + koff,             lA0);
    lds_load16(gA + koff + rowskip16, lA1);
    lds_load16(gB + koff,             lB0);
    lds_load16(gB + koff + rowskip16, lB1);
    __syncthreads();  // staging visible (compiler drains vmcnt before barrier)

    short8 af[4], bfm[4];
    #pragma unroll
    for (int mt = 0; mt < 4; ++mt)
      af[mt] = *(const short8*)&As[(size_t)(wm * 64 + mt * 16 + l15) * BK + quad * 8];
    #pragma unroll
    for (int nt = 0; nt < 4; ++nt)
      bfm[nt] = *(const short8*)&Bs[(size_t)(wn * 64 + nt * 16 + l15) * BK + quad * 8];

    #pragma unroll
    for (int mt = 0; mt < 4; ++mt)
      #pragma unroll
      for (int nt = 0; nt < 4; ++nt)
        acc[mt][nt] = __builtin_amdgcn_mfma_f32_16x16x32_bf16(
            af[mt], bfm[nt], acc[mt][nt], 0, 0, 0);
  }

  // epilogue: per-row max over this block's 128 columns.
  // C/D layout: col = lane&15 (+nt*16 + wn*64), row = quad*4 + reg (+mt*16 + wm*64)
  #pragma unroll
  for (int mt = 0; mt < 4; ++mt) {
    #pragma unroll
    for (int reg = 0; reg < 4; ++reg) {
      float v = fmaxf(fmaxf(acc[mt][0][reg], acc[mt][1][reg]),
                      fmaxf(acc[mt][2][reg], acc[mt][3][reg]));
      // reduce across the 16 lanes of this quad (covers the 16 col values)
      #pragma unroll
      for (int off = 1; off < 16; off <<= 1)
        v = fmaxf(v, __shfl_xor(v, off, 64));
      if (l15 == 0) {
        int r = wm * 64 + mt * 16 + quad * 4 + reg;
        red[wn][r] = v;
      }
    }
  }
  __syncthreads();
  if (tid < BM) {
    float m = fmaxf(red[0][tid], red[1][tid]);
    partial[(size_t)blockIdx.y * Nx + bm0 + tid] = m;
  }
}

// ---- kernel 3: final row max over column blocks + halfnormal transform ------

__global__ __launch_bounds__(256) void rowmax_kernel(
    const float* __restrict__ partial, float* __restrict__ trow, int Nx, int ncb) {
  int r = blockIdx.x * blockDim.x + threadIdx.x;
  if (r >= Nx) return;
  float m = -1e30f;
  for (int cb = 0; cb < ncb; ++cb)
    m = fmaxf(m, partial[(size_t)cb * Nx + r]);
  float x = 1.0f - m;
  const float logc = -0.22579135264472744f;  // 0.5*log(2/pi), sigma=1
  float l = logc - 0.5f * x * x;
  trow[r] = -__expf(l) * l;
}

// ---- kernel 4: deterministic single-block sum -> out[0], out[1] -------------

__global__ __launch_bounds__(1024) void sum_kernel(
    const float* __restrict__ trow, float* __restrict__ out, int n) {
  __shared__ float sdata[16];
  float s = 0.f;
  for (int i = threadIdx.x; i < n; i += 1024) s += trow[i];
  #pragma unroll
  for (int off = 32; off > 0; off >>= 1) s += __shfl_xor(s, off, 64);
  int wave = threadIdx.x >> 6;
  int lane = threadIdx.x & 63;
  if (lane == 0) sdata[wave] = s;
  __syncthreads();
  if (threadIdx.x == 0) {
    float t = 0.f;
    #pragma unroll
    for (int w = 0; w < 16; ++w) t += sdata[w];
    out[0] = t;
    out[1] = t;
  }
}

// ---- launch -----------------------------------------------------------------

extern "C" void kernel_launch(void* const* d_in, const int* in_sizes, int n_in,
                              void* d_out, int out_size, void* d_ws, size_t ws_size,
                              hipStream_t stream) {
  const float* ex = (const float*)d_in[0];
  const float* ey = (const float*)d_in[1];
  const int Nx = in_sizes[0] / D_DIM;   // 8192
  const int Ny = in_sizes[1] / D_DIM;   // 16384
  const int ncb = Ny / BN;              // 128

  char* ws = (char*)d_ws;
  unsigned short* exn = (unsigned short*)ws;                                  // Nx*768 bf16
  unsigned short* eyn = (unsigned short*)(ws + (size_t)Nx * D_DIM * 2);       // Ny*768 bf16
  float* partial = (float*)(ws + (size_t)(Nx + Ny) * D_DIM * 2);              // ncb*Nx f32
  float* trow    = partial + (size_t)ncb * Nx;                                // Nx f32

  norm_cast_kernel<<<Nx / 4, 256, 0, stream>>>(ex, exn, Nx);
  norm_cast_kernel<<<Ny / 4, 256, 0, stream>>>(ey, eyn, Ny);
  gemm_max_kernel<<<dim3(Nx / BM, ncb), 256, 0, stream>>>(exn, eyn, partial, Nx);
  rowmax_kernel<<<(Nx + 255) / 256, 256, 0, stream>>>(partial, trow, Nx, ncb);
  sum_kernel<<<1, 1024, 0, stream>>>(trow, (float*)d_out, Nx);
}

// Round 2
// 373.022 us; speedup vs baseline: 1.0124x; 1.0124x over previous
//
#include <hip/hip_runtime.h>
#include <hip/hip_bf16.h>
#include <cstdint>

#define D_DIM 768
#define BM 128
#define BN 256
#define BK 32

typedef short short8 __attribute__((ext_vector_type(8)));
typedef float floatx16 __attribute__((ext_vector_type(16)));

// ---- helpers ----------------------------------------------------------------

__device__ inline unsigned short f2bf(float f) {
  union { float f; unsigned int u; } v; v.f = f;
  unsigned int u = v.u;
  unsigned int rounding = 0x7FFFu + ((u >> 16) & 1u);  // round-to-nearest-even
  u += rounding;
  return (unsigned short)(u >> 16);
}

__device__ inline void lds_load16(const void* g, void* lds) {
  __builtin_amdgcn_global_load_lds(
      (const __attribute__((address_space(1))) unsigned int*)g,
      (__attribute__((address_space(3))) unsigned int*)lds,
      16, 0, 0);
}

// ---- kernel 1: row L2 norm + normalize + cast to bf16 -----------------------

__global__ __launch_bounds__(256) void norm_cast_kernel(
    const float* __restrict__ X, unsigned short* __restrict__ Y, int nrows) {
  int row = blockIdx.x * 4 + (threadIdx.x >> 6);
  int lane = threadIdx.x & 63;
  if (row >= nrows) return;
  const float4* xr = (const float4*)(X + (size_t)row * D_DIM);
  float4 a = xr[lane];
  float4 b = xr[lane + 64];
  float4 c = xr[lane + 128];
  float ss = a.x*a.x + a.y*a.y + a.z*a.z + a.w*a.w
           + b.x*b.x + b.y*b.y + b.z*b.z + b.w*b.w
           + c.x*c.x + c.y*c.y + c.z*c.z + c.w*c.w;
  #pragma unroll
  for (int off = 32; off > 0; off >>= 1) ss += __shfl_xor(ss, off, 64);
  float s = 1.0f / fmaxf(sqrtf(ss), 1e-8f);
  ushort4 o;
  ushort4* yr = (ushort4*)(Y + (size_t)row * D_DIM);
  o.x = f2bf(a.x * s); o.y = f2bf(a.y * s); o.z = f2bf(a.z * s); o.w = f2bf(a.w * s);
  yr[lane] = o;
  o.x = f2bf(b.x * s); o.y = f2bf(b.y * s); o.z = f2bf(b.z * s); o.w = f2bf(b.w * s);
  yr[lane + 64] = o;
  o.x = f2bf(c.x * s); o.y = f2bf(c.y * s); o.z = f2bf(c.z * s); o.w = f2bf(c.w * s);
  yr[lane + 128] = o;
}

// ---- kernel 2: bf16 MFMA GEMM (S = A . B^T) fused with per-row max ----------
// Block tile 128x256, BK=32. 256 threads = 4 waves in 2x2; wave tile 64x128
// = 2x4 grid of 32x32x16 MFMA. LDS tiles row-major [rows][32] bf16 (64 B/row),
// 16B chunks XOR-swizzled: physical chunk p = j ^ ((row>>1)&3) — makes the
// ds_read_b128 fragment reads conflict-free (row stride 64 B = 16 banks would
// otherwise give 8-way conflicts; round-1 measured 2.5e7 SQ_LDS_BANK_CONFLICT).
// Swizzle is applied on the GLOBAL source address so global_load_lds's
// wave-uniform deposit (base + lane*16) produces the swizzled layout.

__global__ __launch_bounds__(256, 2) void gemm_max_kernel(
    const unsigned short* __restrict__ A,   // exn [Nx x 768] bf16 bits
    const unsigned short* __restrict__ B,   // eyn [Ny x 768] bf16 bits
    float* __restrict__ partial,            // [ncb][Nx]
    int Nx) {
  __shared__ unsigned short As[BM * BK];   // 8 KB
  __shared__ unsigned short Bs[BN * BK];   // 16 KB
  __shared__ float red[2][BM];

  const int tid  = threadIdx.x;
  const int wave = tid >> 6;
  const int lane = tid & 63;
  const int wm = wave >> 1;        // 0..1: row half (64 rows each)
  const int wn = wave & 1;         // 0..1: col half (128 cols each)
  const int l31 = lane & 31;
  const int h   = lane >> 5;       // half-wave
  const int sl  = (l31 >> 1) & 3;  // reader-side swizzle key (base mult of 32)

  const int bm0 = blockIdx.x * BM;
  const int bn0 = blockIdx.y * BN;

  floatx16 acc[2][4];
  #pragma unroll
  for (int mt = 0; mt < 2; ++mt)
    #pragma unroll
    for (int nt = 0; nt < 4; ++nt)
      acc[mt][nt] = (floatx16)(0.f);

  // staging: instr covers 16 rows; lane -> (row = r0 + lane/4, phys chunk lane&3)
  // global chunk j = (lane&3) ^ s(row); s(row) = ((lane>>2)>>1)&3 since r0 % 16 == 0
  const int srow = lane >> 2;
  const int sj = (lane & 3) ^ ((srow >> 1) & 3);
  const char* gA = (const char*)A + ((size_t)(bm0 + wave * 32 + srow) * D_DIM) * 2 + sj * 16;
  const char* gB = (const char*)B + ((size_t)(bn0 + wave * 64 + srow) * D_DIM) * 2 + sj * 16;
  char* lA0 = (char*)As + (size_t)(wave * 32) * 64;   // wave stages 32 A rows
  char* lB0 = (char*)Bs + (size_t)(wave * 64) * 64;   // and 64 B rows
  const size_t g16 = (size_t)16 * D_DIM * 2;          // 16 global rows

  for (int k0 = 0; k0 < D_DIM; k0 += BK) {
    __syncthreads();  // previous tile fully consumed
    size_t ko = (size_t)k0 * 2;
    lds_load16(gA + ko,           lA0);
    lds_load16(gA + ko + g16,     lA0 + 1024);
    lds_load16(gB + ko,           lB0);
    lds_load16(gB + ko + g16,     lB0 + 1024);
    lds_load16(gB + ko + 2 * g16, lB0 + 2048);
    lds_load16(gB + ko + 3 * g16, lB0 + 3072);
    __syncthreads();  // staging visible

    #pragma unroll
    for (int k = 0; k < 2; ++k) {        // two K=16 steps inside the K=32 tile
      const int chunk = h + 2 * k;       // logical 16B chunk (8 bf16) of the row
      short8 af[2], bf[4];
      #pragma unroll
      for (int mt = 0; mt < 2; ++mt)
        af[mt] = *(const short8*)&As[(size_t)(wm * 64 + mt * 32 + l31) * BK
                                     + (size_t)(chunk ^ sl) * 8];
      #pragma unroll
      for (int nt = 0; nt < 4; ++nt)
        bf[nt] = *(const short8*)&Bs[(size_t)(wn * 128 + nt * 32 + l31) * BK
                                     + (size_t)(chunk ^ sl) * 8];
      #pragma unroll
      for (int mt = 0; mt < 2; ++mt)
        #pragma unroll
        for (int nt = 0; nt < 4; ++nt)
          acc[mt][nt] = __builtin_amdgcn_mfma_f32_32x32x16_bf16(
              af[mt], bf[nt], acc[mt][nt], 0, 0, 0);
    }
  }

  // epilogue: per-row max over this block's 256 columns.
  // C/D (32x32): col = l31 (+nt*32 + wn*128), row = (reg&3)+8*(reg>>2)+4*h (+mt*32+wm*64)
  #pragma unroll
  for (int mt = 0; mt < 2; ++mt) {
    #pragma unroll
    for (int reg = 0; reg < 16; ++reg) {
      float v = fmaxf(fmaxf(acc[mt][0][reg], acc[mt][1][reg]),
                      fmaxf(acc[mt][2][reg], acc[mt][3][reg]));
      #pragma unroll
      for (int off = 1; off < 32; off <<= 1)
        v = fmaxf(v, __shfl_xor(v, off, 64));   // reduce over l31 within each half
      if (l31 == 0) {
        int r = wm * 64 + mt * 32 + (reg & 3) + 8 * (reg >> 2) + 4 * h;
        red[wn][r] = v;   // lanes 0 and 32 hit different r (4*h); waves differ in (wn,wm)
      }
    }
  }
  __syncthreads();
  if (tid < BM) {
    float m = fmaxf(red[0][tid], red[1][tid]);
    partial[(size_t)blockIdx.y * Nx + bm0 + tid] = m;
  }
}

// ---- kernel 3: row max over column blocks + halfnormal transform + block sum

__global__ __launch_bounds__(256) void rowmax_kernel(
    const float* __restrict__ partial, float* __restrict__ bsum, int Nx, int ncb) {
  __shared__ float sdata[4];
  int r = blockIdx.x * blockDim.x + threadIdx.x;
  float m = -1e30f;
  for (int cb = 0; cb < ncb; ++cb)
    m = fmaxf(m, partial[(size_t)cb * Nx + r]);
  float x = 1.0f - m;
  const float logc = -0.22579135264472744f;  // 0.5*log(2/pi), sigma=1
  float l = logc - 0.5f * x * x;
  float t = -__expf(l) * l;
  #pragma unroll
  for (int off = 32; off > 0; off >>= 1) t += __shfl_xor(t, off, 64);
  int wave = threadIdx.x >> 6;
  int lane = threadIdx.x & 63;
  if (lane == 0) sdata[wave] = t;
  __syncthreads();
  if (threadIdx.x == 0)
    bsum[blockIdx.x] = sdata[0] + sdata[1] + sdata[2] + sdata[3];
}

// ---- kernel 4: final sum of 32 block partials -> out[0], out[1] -------------

__global__ __launch_bounds__(64) void final_kernel(
    const float* __restrict__ bsum, float* __restrict__ out, int nb) {
  int lane = threadIdx.x;
  float s = (lane < nb) ? bsum[lane] : 0.f;
  #pragma unroll
  for (int off = 32; off > 0; off >>= 1) s += __shfl_xor(s, off, 64);
  if (lane == 0) { out[0] = s; out[1] = s; }
}

// ---- launch -----------------------------------------------------------------

extern "C" void kernel_launch(void* const* d_in, const int* in_sizes, int n_in,
                              void* d_out, int out_size, void* d_ws, size_t ws_size,
                              hipStream_t stream) {
  const float* ex = (const float*)d_in[0];
  const float* ey = (const float*)d_in[1];
  const int Nx = in_sizes[0] / D_DIM;   // 8192
  const int Ny = in_sizes[1] / D_DIM;   // 16384
  const int ncb = Ny / BN;              // 64

  char* ws = (char*)d_ws;
  unsigned short* exn = (unsigned short*)ws;                                  // Nx*768 bf16
  unsigned short* eyn = (unsigned short*)(ws + (size_t)Nx * D_DIM * 2);       // Ny*768 bf16
  float* partial = (float*)(ws + (size_t)(Nx + Ny) * D_DIM * 2);              // ncb*Nx f32
  float* bsum    = partial + (size_t)ncb * Nx;                                // 32 f32

  norm_cast_kernel<<<Nx / 4, 256, 0, stream>>>(ex, exn, Nx);
  norm_cast_kernel<<<Ny / 4, 256, 0, stream>>>(ey, eyn, Ny);
  gemm_max_kernel<<<dim3(Nx / BM, Ny / BN), 256, 0, stream>>>(exn, eyn, partial, Nx);
  rowmax_kernel<<<Nx / 256, 256, 0, stream>>>(partial, bsum, Nx, ncb);
  final_kernel<<<1, 64, 0, stream>>>(bsum, (float*)d_out, Nx / 256);
}